// Round 1
// baseline (2767.883 us; speedup 1.0000x reference)
//
#include <hip/hip_runtime.h>

#define B_ 16
#define C_ 64
#define H_ 128
#define W_ 256
#define K_ 9
#define PLANE_ (H_*W_)
#define IMG_ ((size_t)C_*H_*W_)
#define TOT_ ((size_t)B_*C_*H_*W_)

// Transpose weights from [co][ci][k] to [ci][k][co] so that the conv inner
// loop over co reads contiguous floats (block-uniform -> s_load_dwordx).
__global__ __launch_bounds__(256) void transpose_w_kernel(const float* __restrict__ w,
                                                          float* __restrict__ wT) {
  int i = blockIdx.x * 256 + threadIdx.x;
  if (i >= C_*C_*K_) return;
  int k  = i % K_;
  int ci = (i / K_) % C_;
  int co = i / (K_ * C_);
  wT[(ci*K_ + k)*C_ + co] = w[i];
}

// 1D conv (cross-correlation, zero-pad 4) along W (ALONG_W=true) or along H.
// Block = one (b, h) output row; thread = one w column; each thread computes
// all 64 output channels in registers.
template<bool ALONG_W>
__global__ __launch_bounds__(256) void conv_kernel(const float* __restrict__ in,
                                                   float* __restrict__ out,
                                                   const float* __restrict__ wT,
                                                   const float* __restrict__ bias) {
  const int h = blockIdx.x;     // 0..H-1
  const int b = blockIdx.y;     // 0..B-1
  const int w = threadIdx.x;    // 0..W-1
  const float* inb = in + (size_t)b * IMG_;

  float acc[C_];
#pragma unroll
  for (int co = 0; co < C_; ++co) acc[co] = bias[co];

#pragma unroll 1
  for (int ci = 0; ci < C_; ++ci) {
    const float* p = inb + (size_t)ci * PLANE_;
    float xv[K_];
    if (ALONG_W) {
#pragma unroll
      for (int k = 0; k < K_; ++k) {
        int ww = w + k - 4;
        xv[k] = ((unsigned)ww < (unsigned)W_) ? p[h*W_ + ww] : 0.f;
      }
    } else {
#pragma unroll
      for (int k = 0; k < K_; ++k) {
        int hh = h + k - 4;
        xv[k] = ((unsigned)hh < (unsigned)H_) ? p[hh*W_ + w] : 0.f;
      }
    }
#pragma unroll
    for (int k = 0; k < K_; ++k) {
      const float* wp = wT + (ci*K_ + k)*C_;   // block-uniform, contiguous in co
#pragma unroll
      for (int co = 0; co < C_; ++co) acc[co] = fmaf(xv[k], wp[co], acc[co]);
    }
  }

  float* ob = out + (size_t)b * IMG_ + h*W_ + w;
#pragma unroll
  for (int co = 0; co < C_; ++co) ob[(size_t)co * PLANE_] = acc[co];
}

// Scan along H, in-place in buf (buf holds conv+bias; boundary row taken from
// xprev). Thread = one (b,c,w) column; fully coalesced (w consecutive).
__global__ __launch_bounds__(256) void scanH_kernel(float* __restrict__ buf,
                                                    const float* __restrict__ xprev,
                                                    int reverse) {
  int idx = blockIdx.x * 256 + threadIdx.x;   // over B*C*W
  int w  = idx & (W_ - 1);
  int bc = idx >> 8;
  long long col = (long long)bc * PLANE_ + w;
  int h0 = reverse ? H_ - 1 : 0;
  int dh = reverse ? -W_ : W_;
  long long off = col + (long long)h0 * W_;
  float y = xprev[off];
  buf[off] = y;
  for (int i = 1; i < H_; ++i) {
    off += dh;
    float cv = buf[off];
    y = fmaxf(cv + y, 0.f);
    buf[off] = y;
  }
}

// Scan along W, in-place in buf. Block = (b, pair of channels); LDS-tiled in
// 32-wide w chunks so global access stays coalesced; scan runs on the
// LDS-resident tile (pad 33 -> conflict-free).
__global__ __launch_bounds__(256) void scanW_kernel(float* __restrict__ buf,
                                                    const float* __restrict__ xprev,
                                                    int reverse) {
  __shared__ float tile[2][H_][33];
  const int b  = blockIdx.y;
  const int c0 = blockIdx.x * 2;
  const int t  = threadIdx.x;
  const int cs = t >> 7;         // 0..1
  const int hs = t & (H_ - 1);   // 0..127
  const size_t base = ((size_t)(b*C_ + c0)) * PLANE_;
  const int wb = reverse ? W_ - 1 : 0;
  float carry = 0.f;

  for (int chunk = 0; chunk < W_/32; ++chunk) {
    const int w0 = (reverse ? (W_/32 - 1 - chunk) : chunk) * 32;
#pragma unroll
    for (int j = 0; j < 32; ++j) {
      int flat = t + 256*j;                 // 0..8191
      int wl = flat & 31;
      int hh = (flat >> 5) & (H_ - 1);
      int cc = flat >> 12;
      tile[cc][hh][wl] = buf[base + (size_t)cc*PLANE_ + hh*W_ + w0 + wl];
    }
    __syncthreads();
    for (int s = 0; s < 32; ++s) {
      int wl = reverse ? 31 - s : s;
      int w = w0 + wl;
      float v;
      if (w == wb) v = xprev[base + (size_t)cs*PLANE_ + hs*W_ + w];
      else         v = fmaxf(tile[cs][hs][wl] + carry, 0.f);
      carry = v;
      tile[cs][hs][wl] = v;
    }
    __syncthreads();
#pragma unroll
    for (int j = 0; j < 32; ++j) {
      int flat = t + 256*j;
      int wl = flat & 31;
      int hh = (flat >> 5) & (H_ - 1);
      int cc = flat >> 12;
      buf[base + (size_t)cc*PLANE_ + hh*W_ + w0 + wl] = tile[cc][hh][wl];
    }
    __syncthreads();
  }
}

extern "C" void kernel_launch(void* const* d_in, const int* in_sizes, int n_in,
                              void* d_out, int out_size, void* d_ws, size_t ws_size,
                              hipStream_t stream) {
  const float* x    = (const float*)d_in[0];
  const float* w_ud = (const float*)d_in[1];
  const float* b_ud = (const float*)d_in[2];
  const float* w_du = (const float*)d_in[3];
  const float* b_du = (const float*)d_in[4];
  const float* w_lr = (const float*)d_in[5];
  const float* b_lr = (const float*)d_in[6];
  const float* w_rl = (const float*)d_in[7];
  const float* b_rl = (const float*)d_in[8];

  // Workspace layout: [ big ping buffer TOT_ floats ][ 4x transposed weights ]
  float* bufW = (float*)d_ws;
  float* wTs  = (float*)((char*)d_ws + TOT_ * sizeof(float));
  float* wT_ud = wTs + 0 * (C_*C_*K_);
  float* wT_du = wTs + 1 * (C_*C_*K_);
  float* wT_lr = wTs + 2 * (C_*C_*K_);
  float* wT_rl = wTs + 3 * (C_*C_*K_);
  float* bufO = (float*)d_out;

  dim3 tg((C_*C_*K_ + 255) / 256);
  transpose_w_kernel<<<tg, 256, 0, stream>>>(w_ud, wT_ud);
  transpose_w_kernel<<<tg, 256, 0, stream>>>(w_du, wT_du);
  transpose_w_kernel<<<tg, 256, 0, stream>>>(w_lr, wT_lr);
  transpose_w_kernel<<<tg, 256, 0, stream>>>(w_rl, wT_rl);

  dim3 cg(H_, B_);
  dim3 sg(C_/2, B_);

  // sweep 1: ud (axis H, forward) — conv along W
  conv_kernel<true><<<cg, 256, 0, stream>>>(x, bufW, wT_ud, b_ud);
  scanH_kernel<<<1024, 256, 0, stream>>>(bufW, x, 0);

  // sweep 2: du (axis H, reverse)
  conv_kernel<true><<<cg, 256, 0, stream>>>(bufW, bufO, wT_du, b_du);
  scanH_kernel<<<1024, 256, 0, stream>>>(bufO, bufW, 1);

  // sweep 3: lr (axis W, forward) — conv along H
  conv_kernel<false><<<cg, 256, 0, stream>>>(bufO, bufW, wT_lr, b_lr);
  scanW_kernel<<<sg, 256, 0, stream>>>(bufW, bufO, 0);

  // sweep 4: rl (axis W, reverse)
  conv_kernel<false><<<cg, 256, 0, stream>>>(bufW, bufO, wT_rl, b_rl);
  scanW_kernel<<<sg, 256, 0, stream>>>(bufO, bufW, 1);
}

// Round 2
// 609.261 us; speedup vs baseline: 4.5430x; 4.5430x over previous
//
#include <hip/hip_runtime.h>

#define B_ 16
#define C_ 64
#define H_ 128
#define W_ 256
#define K_ 9
#define KDIM_ (K_*C_)            // 576
#define TOT_ ((size_t)B_*C_*H_*W_)

typedef __attribute__((ext_vector_type(8))) short short8_t;
typedef __attribute__((ext_vector_type(4))) float f32x4;

static __device__ __forceinline__ float bf2f(unsigned short u) {
  union { unsigned int i; float f; } v; v.i = ((unsigned int)u) << 16; return v.f;
}
static __device__ __forceinline__ unsigned short f2bf(float f) {
  union { float f; unsigned int i; } v; v.f = f;
  unsigned int r = v.i + 0x7FFF + ((v.i >> 16) & 1);   // RNE
  return (unsigned short)(r >> 16);
}

// Pack weights [co][ci][kk] fp32 -> A_t[co][kk*64+ci] bf16 (K ordering kk-major).
__global__ __launch_bounds__(256) void prep_w(const float* __restrict__ w,
                                              unsigned short* __restrict__ At) {
  int idx = blockIdx.x * 256 + threadIdx.x;
  if (idx >= C_ * KDIM_) return;
  int co = idx / KDIM_, rem = idx % KDIM_;
  int kk = rem >> 6, ci = rem & 63;
  At[idx] = f2bf(w[((size_t)co * C_ + ci) * K_ + kk]);
}

// fp32 NCHW -> bf16 ci-minor [b][h][w][ci]
__global__ __launch_bounds__(256) void transpose_in(const float* __restrict__ x,
                                                    unsigned short* __restrict__ Xt) {
  __shared__ float tile[64][65];
  const int w0 = blockIdx.x * 64, h = blockIdx.y, b = blockIdx.z;
  const int t = threadIdx.x;
#pragma unroll
  for (int rep = 0; rep < 16; ++rep) {
    int idx = rep * 256 + t;
    int ci = idx >> 6, wl = idx & 63;
    tile[ci][wl] = x[((size_t)(b * C_ + ci) * H_ + h) * W_ + w0 + wl];
  }
  __syncthreads();
#pragma unroll
  for (int rep = 0; rep < 16; ++rep) {
    int idx = rep * 256 + t;
    int wl = idx >> 6, ci = idx & 63;
    Xt[((size_t)(b * H_ + h) * W_ + w0 + wl) * C_ + ci] = f2bf(tile[ci][wl]);
  }
}

// fp32 ci-minor -> fp32 NCHW (final output)
__global__ __launch_bounds__(256) void transpose_out(const float* __restrict__ F,
                                                     float* __restrict__ out) {
  __shared__ float tile[64][65];
  const int w0 = blockIdx.x * 64, h = blockIdx.y, b = blockIdx.z;
  const int t = threadIdx.x;
#pragma unroll
  for (int rep = 0; rep < 16; ++rep) {
    int idx = rep * 256 + t;
    int wl = idx >> 6, ci = idx & 63;
    tile[ci][wl] = F[((size_t)(b * H_ + h) * W_ + w0 + wl) * C_ + ci];
  }
  __syncthreads();
#pragma unroll
  for (int rep = 0; rep < 16; ++rep) {
    int idx = rep * 256 + t;
    int ci = idx >> 6, wl = idx & 63;
    out[((size_t)(b * C_ + ci) * H_ + h) * W_ + w0 + wl] = tile[ci][wl];
  }
}

// MFMA conv. MODE 0: conv along W, block=(h,b), n = w (256).
//            MODE 1: conv along H, block=(w-pair,b), n = h per strip (2 strips x 128).
// X,Y bf16 ci-minor; At bf16 [co][kk*64+ci]; bias fp32.
// LDS tile rows = spatial position (+4 zero-pad both ends), 64 bf16 (128B) per row,
// XOR-swizzled per 16B chunk: slot' = chunk ^ (row&7)  -> conflict-free ds_read_b128.
template<int MODE>
__global__ __launch_bounds__(256) void conv_mfma(const unsigned short* __restrict__ X,
                                                 unsigned short* __restrict__ Y,
                                                 const unsigned short* __restrict__ At,
                                                 const float* __restrict__ bias) {
  __shared__ unsigned short lds[272 * 64];   // 34816 B
  const int t = threadIdx.x;
  const int b = blockIdx.y;
  const int lane = t & 63, wave = t >> 6;
  const int llo = lane & 15, lhi = lane >> 4;

  // ---- stage x tile into LDS (swizzled) ----
  if (MODE == 0) {
    const int h = blockIdx.x;
    const size_t rowbase = ((size_t)(b * H_ + h) * W_) * C_;
#pragma unroll
    for (int it = 0; it < 8; ++it) {
      int q = t + it * 256;                 // 2048 16B-chunks: 256 rows x 8 slots
      int r = 4 + (q >> 3), slot = q & 7, w = r - 4;
      short8_t v = *(const short8_t*)(X + rowbase + (size_t)w * C_ + slot * 8);
      *(short8_t*)((char*)lds + r * 128 + ((slot ^ (r & 7)) * 16)) = v;
    }
    if (t < 64) {                            // zero pad rows 0..3, 260..263
      short8_t z = {0,0,0,0,0,0,0,0};
      int q = t >> 3, slot = t & 7;
      int r = (q < 4) ? q : 256 + q;
      *(short8_t*)((char*)lds + r * 128 + slot * 16) = z;
    }
  } else {
    const int w0 = blockIdx.x * 2;
#pragma unroll
    for (int it = 0; it < 8; ++it) {
      int q = t + it * 256;                 // 2 strips x 128 rows x 8 slots
      int s = q >> 10, rq = (q >> 3) & 127, slot = q & 7;
      int r = 4 + rq, h = rq;
      short8_t v = *(const short8_t*)(X + ((size_t)(b * H_ + h) * W_ + w0 + s) * C_ + slot * 8);
      *(short8_t*)((char*)lds + s * (136 * 128) + r * 128 + ((slot ^ (r & 7)) * 16)) = v;
    }
    if (t < 128) {                           // zero pad rows 0..3, 132..135 per strip
      short8_t z = {0,0,0,0,0,0,0,0};
      int s = t >> 6, q = (t >> 3) & 7, slot = t & 7;
      int r = (q < 4) ? q : 128 + q;
      *(short8_t*)((char*)lds + s * (136 * 128) + r * 128 + slot * 16) = z;
    }
  }
  __syncthreads();

  // wave -> output sub-tile
  int nbase, sbase;
  if (MODE == 0) { nbase = wave * 64; sbase = 0; }
  else           { nbase = (wave & 1) * 64; sbase = (wave >> 1) * (136 * 128); }

  f32x4 acc[4][4];
#pragma unroll
  for (int i = 0; i < 4; ++i)
#pragma unroll
    for (int j = 0; j < 4; ++j) { f32x4 z = {0.f,0.f,0.f,0.f}; acc[i][j] = z; }

  const char* ldsb = (const char*)lds + sbase;
  const unsigned short* Abase = At + (size_t)llo * KDIM_;

#pragma unroll 2
  for (int step = 0; step < 18; ++step) {     // K = 576 = 18 x 32
    const int kk = step >> 1;
    const int cg = (step & 1) * 4 + lhi;      // 16B ci-chunk index 0..7
    short8_t a[4], bf[4];
#pragma unroll
    for (int j = 0; j < 4; ++j)
      a[j] = *(const short8_t*)(Abase + (size_t)(j * 16) * KDIM_ + step * 32 + lhi * 8);
#pragma unroll
    for (int i = 0; i < 4; ++i) {
      int r = nbase + i * 16 + llo + kk;      // spatial row in LDS (pad offset folded)
      bf[i] = *(const short8_t*)(ldsb + r * 128 + ((cg ^ (r & 7)) * 16));
    }
#pragma unroll
    for (int i = 0; i < 4; ++i)
#pragma unroll
      for (int j = 0; j < 4; ++j)
        acc[i][j] = __builtin_amdgcn_mfma_f32_16x16x32_bf16(a[j], bf[i], acc[i][j], 0, 0, 0);
  }

  // ---- epilogue: +bias, pack 4 consecutive co as bf16x4 (8B stores) ----
#pragma unroll
  for (int j = 0; j < 4; ++j) {
    const int cb = j * 16 + lhi * 4;
    const float4 bv = *(const float4*)(bias + cb);
#pragma unroll
    for (int i = 0; i < 4; ++i) {
      const int n = nbase + i * 16 + llo;
      size_t off;
      if (MODE == 0) { int h = blockIdx.x; int w = n;
        off = ((size_t)(b * H_ + h) * W_ + w) * C_ + cb; }
      else { int w = blockIdx.x * 2 + (wave >> 1); int h = n;
        off = ((size_t)(b * H_ + h) * W_ + w) * C_ + cb; }
      short4 o;
      o.x = (short)f2bf(acc[i][j][0] + bv.x);
      o.y = (short)f2bf(acc[i][j][1] + bv.y);
      o.z = (short)f2bf(acc[i][j][2] + bv.z);
      o.w = (short)f2bf(acc[i][j][3] + bv.w);
      *(short4*)(Y + off) = o;
    }
  }
}

// Directional scan along H. buf holds conv+bias (bf16 ci-minor), in-place.
__global__ __launch_bounds__(256) void scanH(unsigned short* __restrict__ buf,
                                             const unsigned short* __restrict__ prev,
                                             int reverse) {
  int idx = blockIdx.x * 256 + threadIdx.x;   // B*W*C
  int ci = idx & 63;
  int w  = (idx >> 6) & 255;
  int b  = idx >> 14;
  const int h0 = reverse ? H_ - 1 : 0;
  const ptrdiff_t dh = (reverse ? -1 : 1) * (ptrdiff_t)(W_ * C_);
  size_t off = ((size_t)(b * H_ + h0) * W_ + w) * C_ + ci;
  float y = bf2f(prev[off]);
  buf[off] = prev[off];                        // boundary row copied unchanged
  for (int s = 1; s < H_; ++s) {
    off += dh;
    float c = bf2f(buf[off]);
    y = fmaxf(c + y, 0.f);
    buf[off] = f2bf(y);
  }
}

// Directional scan along W. FP32OUT=1: write fp32 ci-minor to fout instead.
template<int REVERSE, int FP32OUT>
__global__ __launch_bounds__(256) void scanW(unsigned short* __restrict__ buf,
                                             const unsigned short* __restrict__ prev,
                                             float* __restrict__ fout) {
  int idx = blockIdx.x * 256 + threadIdx.x;   // B*H*C
  int ci = idx & 63;
  int h  = (idx >> 6) & 127;
  int b  = idx >> 13;
  const int w0 = REVERSE ? W_ - 1 : 0;
  const ptrdiff_t dw = (REVERSE ? -1 : 1) * (ptrdiff_t)C_;
  size_t off = ((size_t)(b * H_ + h) * W_ + w0) * C_ + ci;
  float y = bf2f(prev[off]);
  if (FP32OUT) fout[off] = y; else buf[off] = prev[off];
  for (int s = 1; s < W_; ++s) {
    off += dw;
    float c = bf2f(buf[off]);
    y = fmaxf(c + y, 0.f);
    if (FP32OUT) fout[off] = y; else buf[off] = f2bf(y);
  }
}

extern "C" void kernel_launch(void* const* d_in, const int* in_sizes, int n_in,
                              void* d_out, int out_size, void* d_ws, size_t ws_size,
                              hipStream_t stream) {
  const float* x    = (const float*)d_in[0];
  const float* w_ud = (const float*)d_in[1];
  const float* b_ud = (const float*)d_in[2];
  const float* w_du = (const float*)d_in[3];
  const float* b_du = (const float*)d_in[4];
  const float* w_lr = (const float*)d_in[5];
  const float* b_lr = (const float*)d_in[6];
  const float* w_rl = (const float*)d_in[7];
  const float* b_rl = (const float*)d_in[8];

  // ws layout (bytes): A[0,64M) B[64M,128M) Cc[128M,192M) F fp32 [192M,320M) At x4
  unsigned short* A  = (unsigned short*)d_ws;
  unsigned short* Bb = (unsigned short*)((char*)d_ws + 67108864);
  unsigned short* Cc = (unsigned short*)((char*)d_ws + 134217728);
  float*          F  = (float*)((char*)d_ws + 201326592);
  unsigned short* At = (unsigned short*)((char*)d_ws + 335544320);
  unsigned short* At_ud = At + 0 * (C_ * KDIM_);
  unsigned short* At_du = At + 1 * (C_ * KDIM_);
  unsigned short* At_lr = At + 2 * (C_ * KDIM_);
  unsigned short* At_rl = At + 3 * (C_ * KDIM_);

  dim3 pg((C_ * KDIM_ + 255) / 256);
  prep_w<<<pg, 256, 0, stream>>>(w_ud, At_ud);
  prep_w<<<pg, 256, 0, stream>>>(w_du, At_du);
  prep_w<<<pg, 256, 0, stream>>>(w_lr, At_lr);
  prep_w<<<pg, 256, 0, stream>>>(w_rl, At_rl);

  transpose_in<<<dim3(4, H_, B_), 256, 0, stream>>>(x, A);

  // sweep 1: ud (H fwd), conv along W
  conv_mfma<0><<<dim3(H_, B_), 256, 0, stream>>>(A, Bb, At_ud, b_ud);
  scanH<<<1024, 256, 0, stream>>>(Bb, A, 0);
  // sweep 2: du (H rev)
  conv_mfma<0><<<dim3(H_, B_), 256, 0, stream>>>(Bb, Cc, At_du, b_du);
  scanH<<<1024, 256, 0, stream>>>(Cc, Bb, 1);
  // sweep 3: lr (W fwd), conv along H
  conv_mfma<1><<<dim3(128, B_), 256, 0, stream>>>(Cc, A, At_lr, b_lr);
  scanW<0, 0><<<512, 256, 0, stream>>>(A, Cc, nullptr);
  // sweep 4: rl (W rev), scan writes fp32
  conv_mfma<1><<<dim3(128, B_), 256, 0, stream>>>(A, Bb, At_rl, b_rl);
  scanW<1, 1><<<512, 256, 0, stream>>>(Bb, A, F);

  transpose_out<<<dim3(4, H_, B_), 256, 0, stream>>>(F, (float*)d_out);
}

// Round 3
// 449.926 us; speedup vs baseline: 6.1519x; 1.3541x over previous
//
#include <hip/hip_runtime.h>

#define B_ 16
#define C_ 64
#define H_ 128
#define W_ 256
#define K_ 9
#define KDIM_ (K_*C_)            // 576
#define TOT_ ((size_t)B_*C_*H_*W_)

typedef __attribute__((ext_vector_type(8))) short short8_t;
typedef __attribute__((ext_vector_type(4))) float f32x4;

static __device__ __forceinline__ float bf2f(unsigned short u) {
  union { unsigned int i; float f; } v; v.i = ((unsigned int)u) << 16; return v.f;
}
static __device__ __forceinline__ unsigned short f2bf(float f) {
  union { float f; unsigned int i; } v; v.f = f;
  unsigned int r = v.i + 0x7FFF + ((v.i >> 16) & 1);   // RNE
  return (unsigned short)(r >> 16);
}

// async global->LDS, 16B per lane; lds ptr must be wave-uniform
static __device__ __forceinline__ void gload_lds16(const void* g, void* l) {
  __builtin_amdgcn_global_load_lds(
      (const __attribute__((address_space(1))) unsigned int*)g,
      (__attribute__((address_space(3))) unsigned int*)l, 16, 0, 0);
}

// Weights [co][ci][kk] fp32 -> A2 chunk layout: chunk c = k>>3 (k = kk*64+ci),
// A2[(c*64 + co)*8 + (k&7)] bf16. One 16B chunk = 8 consecutive k for one co.
__global__ __launch_bounds__(256) void prep_w(const float* __restrict__ w,
                                              unsigned short* __restrict__ A2) {
  int idx = blockIdx.x * 256 + threadIdx.x;
  if (idx >= C_ * KDIM_) return;
  int co = idx / KDIM_, k = idx % KDIM_;
  int ci = k & 63, kk = k >> 6;
  A2[((size_t)(k >> 3) * 64 + co) * 8 + (k & 7)] =
      f2bf(w[((size_t)co * C_ + ci) * K_ + kk]);
}

// fp32 NCHW -> bf16 ci-minor [b][h][w][ci] (packed uint stores)
__global__ __launch_bounds__(256) void transpose_in(const float* __restrict__ x,
                                                    unsigned short* __restrict__ Xt) {
  __shared__ float tile[64][65];
  const int w0 = blockIdx.x * 64, h = blockIdx.y, b = blockIdx.z;
  const int t = threadIdx.x;
#pragma unroll
  for (int rep = 0; rep < 16; ++rep) {
    int idx = rep * 256 + t;
    int ci = idx >> 6, wl = idx & 63;
    tile[ci][wl] = x[((size_t)(b * C_ + ci) * H_ + h) * W_ + w0 + wl];
  }
  __syncthreads();
#pragma unroll
  for (int rep = 0; rep < 8; ++rep) {
    int idx = rep * 256 + t;
    int wl = idx >> 5, cp = idx & 31;
    unsigned v = (unsigned)f2bf(tile[cp*2][wl]) | ((unsigned)f2bf(tile[cp*2+1][wl]) << 16);
    *(unsigned*)(Xt + ((size_t)(b * H_ + h) * W_ + w0 + wl) * C_ + cp * 2) = v;
  }
}

// bf16 ci-minor -> fp32 NCHW (final output)
__global__ __launch_bounds__(256) void transpose_out(const unsigned short* __restrict__ F,
                                                     float* __restrict__ out) {
  __shared__ float tile[64][65];
  const int w0 = blockIdx.x * 64, h = blockIdx.y, b = blockIdx.z;
  const int t = threadIdx.x;
#pragma unroll
  for (int rep = 0; rep < 8; ++rep) {
    int idx = rep * 256 + t;
    int wl = idx >> 5, cp = idx & 31;
    unsigned v = *(const unsigned*)(F + ((size_t)(b * H_ + h) * W_ + w0 + wl) * C_ + cp * 2);
    tile[cp*2][wl]   = bf2f((unsigned short)v);
    tile[cp*2+1][wl] = bf2f((unsigned short)(v >> 16));
  }
  __syncthreads();
#pragma unroll
  for (int rep = 0; rep < 16; ++rep) {
    int idx = rep * 256 + t;
    int ci = idx >> 6, wl = idx & 63;
    out[((size_t)(b * C_ + ci) * H_ + h) * W_ + w0 + wl] = tile[ci][wl];
  }
}

// Persistent-block MFMA conv, 2-phase pipeline, all operands in LDS.
// MODE 0: conv along W; block=(h-group of 8, b); per row, wave wv owns w in [wv*64,+64).
// MODE 1: conv along H; block=(w-group of 16, b); 8 column-pairs; wave -> (strip=wv>>1, half=wv&1).
// x tiles swizzled per 16B chunk: LDS slot s of row r holds chunk s^(r&7); staged via
// linear global_load_lds with pre-swizzled per-lane global source.
template<int MODE>
__global__ __launch_bounds__(256, 1) void conv2(const unsigned short* __restrict__ X,
                                                unsigned short* __restrict__ Y,
                                                const unsigned short* __restrict__ A2,
                                                const float* __restrict__ bias) {
  constexpr int XBUF  = (MODE == 0) ? 33792 : 34816;   // bytes per x buffer
  constexpr int STRIP = 17408;                          // MODE1 strip bytes (136*128)
  __shared__ __align__(16) char lds[73728 + 2 * XBUF];
  char* Alds  = lds;
  char* xbuf0 = lds + 73728;
  char* xbuf1 = xbuf0 + XBUF;

  const int t = threadIdx.x, b = blockIdx.y;
  const int lane = t & 63, wv = t >> 6;
  const int llo = lane & 15, lhi = lane >> 4;
  const int base0 = (MODE == 0) ? blockIdx.x * 8 : blockIdx.x * 16;

  // ---- prologue: A -> LDS (linear 72KB), zero pads, stage iter 0 ----
#pragma unroll
  for (int i = 0; i < 18; ++i) {
    int m = i * 4 + wv;                       // 72 x 1KB instructions
    gload_lds16(A2 + ((size_t)m * 64 + lane) * 8, Alds + m * 1024);
  }
  if (MODE == 0) {
    if (t < 128) {                            // pad rows 0..3, 260..263 x 2 bufs
      short8_t z = {0,0,0,0,0,0,0,0};
      int bufId = t >> 6, q = (t >> 3) & 7, slot = t & 7;
      int r = (q < 4) ? q : 256 + q;
      *(short8_t*)((bufId ? xbuf1 : xbuf0) + r * 128 + slot * 16) = z;
    }
  } else {
    {                                         // 256 pad chunks: 2 bufs x 2 strips x 8 rows x 8 slots
      short8_t z = {0,0,0,0,0,0,0,0};
      int bufId = t >> 7, s = (t >> 6) & 1, q = (t >> 3) & 7, slot = t & 7;
      int r = (q < 4) ? q : 128 + q;
      *(short8_t*)((bufId ? xbuf1 : xbuf0) + s * STRIP + r * 128 + slot * 16) = z;
    }
  }

  auto stageM0 = [&](char* xb, int h) {
    const char* src = (const char*)X + ((size_t)(b * H_ + h) * W_) * 128;
#pragma unroll
    for (int j = 0; j < 8; ++j) {
      int row0 = 4 + wv * 64 + j * 8;
      int r = row0 + (lane >> 3);
      int w = r - 4;
      int chunk = (lane & 7) ^ (r & 7);
      gload_lds16(src + (size_t)w * 128 + chunk * 16, xb + row0 * 128);
    }
  };
  auto stageM1 = [&](char* xb, int w0) {
#pragma unroll
    for (int j = 0; j < 8; ++j) {
      int m = wv * 8 + j;                     // 0..31
      int s = m >> 4;
      int row0 = 4 + (m & 15) * 8;
      int r = row0 + (lane >> 3);
      int h = r - 4;
      int chunk = (lane & 7) ^ (r & 7);
      gload_lds16((const char*)X + ((size_t)(b * H_ + h) * W_ + w0 + s) * 128 + chunk * 16,
                  xb + s * STRIP + row0 * 128);
    }
  };

  if (MODE == 0) stageM0(xbuf0, base0); else stageM1(xbuf0, base0);
  __syncthreads();   // drains A-load + stage0

  int nbase, sbase;
  if (MODE == 0) { nbase = wv * 64; sbase = 0; }
  else           { nbase = (wv & 1) * 64; sbase = (wv >> 1) * STRIP; }

  for (int it = 0; it < 8; ++it) {
    char* cur = (it & 1) ? xbuf1 : xbuf0;
    char* nxt = (it & 1) ? xbuf0 : xbuf1;
    if (it + 1 < 8) {                          // issue next stage BEFORE compute
      if (MODE == 0) stageM0(nxt, base0 + it + 1);
      else           stageM1(nxt, base0 + (it + 1) * 2);
    }

    const char* xb = cur + sbase;
    f32x4 acc[4][4];
#pragma unroll
    for (int i = 0; i < 4; ++i)
#pragma unroll
      for (int j = 0; j < 4; ++j) { f32x4 z = {0.f,0.f,0.f,0.f}; acc[i][j] = z; }

#pragma unroll 2
    for (int step = 0; step < 18; ++step) {
      const int kk = step >> 1;
      const int cg = (step & 1) * 4 + lhi;
      short8_t a[4], bfr[4];
#pragma unroll
      for (int j = 0; j < 4; ++j)
        a[j] = *(const short8_t*)(Alds + (size_t)((step * 4 + lhi) * 64 + j * 16 + llo) * 16);
#pragma unroll
      for (int i = 0; i < 4; ++i) {
        int r = nbase + i * 16 + llo + kk;
        bfr[i] = *(const short8_t*)(xb + r * 128 + ((cg ^ (r & 7)) * 16));
      }
#pragma unroll
      for (int i = 0; i < 4; ++i)
#pragma unroll
        for (int j = 0; j < 4; ++j)
          acc[i][j] = __builtin_amdgcn_mfma_f32_16x16x32_bf16(a[j], bfr[i], acc[i][j], 0, 0, 0);
    }

    // epilogue: +bias, pack 4 consecutive co (8B stores)
#pragma unroll
    for (int j = 0; j < 4; ++j) {
      const int cb = j * 16 + lhi * 4;
      const float4 bv = *(const float4*)(bias + cb);
#pragma unroll
      for (int i = 0; i < 4; ++i) {
        const int n = nbase + i * 16 + llo;
        size_t off;
        if (MODE == 0) { int h = base0 + it;
          off = ((size_t)(b * H_ + h) * W_ + n) * C_ + cb; }
        else { int w = base0 + it * 2 + (wv >> 1);
          off = ((size_t)(b * H_ + n) * W_ + w) * C_ + cb; }
        short4 o;
        o.x = (short)f2bf(acc[i][j][0] + bv.x);
        o.y = (short)f2bf(acc[i][j][1] + bv.y);
        o.z = (short)f2bf(acc[i][j][2] + bv.z);
        o.w = (short)f2bf(acc[i][j][3] + bv.w);
        *(short4*)(Y + off) = o;
      }
    }
    __syncthreads();   // drains stage(it+1); by now its HBM latency is covered
  }
}

// Scan along H, in-place, 2 ci (uint) per thread, depth-2 prefetch.
template<int REV>
__global__ __launch_bounds__(256) void scanH(unsigned short* __restrict__ buf,
                                             const unsigned short* __restrict__ prev) {
  int idx = blockIdx.x * 256 + threadIdx.x;      // B*W*32
  int cp = idx & 31, w = (idx >> 5) & 255, b = idx >> 13;
  const ptrdiff_t dh = (REV ? -1 : 1) * (ptrdiff_t)(W_ * C_);
  size_t off = ((size_t)(b * H_ + (REV ? H_ - 1 : 0)) * W_ + w) * C_ + cp * 2;
  unsigned pv = *(const unsigned*)(prev + off);
  *(unsigned*)(buf + off) = pv;
  float y0 = bf2f((unsigned short)pv), y1 = bf2f((unsigned short)(pv >> 16));
  unsigned c1 = *(const unsigned*)(buf + off + dh);
  unsigned c2 = *(const unsigned*)(buf + off + 2 * dh);
  for (int s = 1; s < H_; ++s) {
    off += dh;
    unsigned nx = (s + 2 < H_) ? *(const unsigned*)(buf + off + 2 * dh) : 0u;
    y0 = fmaxf(bf2f((unsigned short)c1) + y0, 0.f);
    y1 = fmaxf(bf2f((unsigned short)(c1 >> 16)) + y1, 0.f);
    *(unsigned*)(buf + off) = (unsigned)f2bf(y0) | ((unsigned)f2bf(y1) << 16);
    c1 = c2; c2 = nx;
  }
}

// Scan along W, in-place bf16, 2 ci per thread, depth-2 prefetch.
template<int REV>
__global__ __launch_bounds__(256) void scanW(unsigned short* __restrict__ buf,
                                             const unsigned short* __restrict__ prev) {
  int idx = blockIdx.x * 256 + threadIdx.x;      // B*H*32
  int cp = idx & 31, h = (idx >> 5) & 127, b = idx >> 12;
  const ptrdiff_t dw = (REV ? -1 : 1) * (ptrdiff_t)C_;
  size_t off = ((size_t)(b * H_ + h) * W_ + (REV ? W_ - 1 : 0)) * C_ + cp * 2;
  unsigned pv = *(const unsigned*)(prev + off);
  *(unsigned*)(buf + off) = pv;
  float y0 = bf2f((unsigned short)pv), y1 = bf2f((unsigned short)(pv >> 16));
  unsigned c1 = *(const unsigned*)(buf + off + dw);
  unsigned c2 = *(const unsigned*)(buf + off + 2 * dw);
  for (int s = 1; s < W_; ++s) {
    off += dw;
    unsigned nx = (s + 2 < W_) ? *(const unsigned*)(buf + off + 2 * dw) : 0u;
    y0 = fmaxf(bf2f((unsigned short)c1) + y0, 0.f);
    y1 = fmaxf(bf2f((unsigned short)(c1 >> 16)) + y1, 0.f);
    *(unsigned*)(buf + off) = (unsigned)f2bf(y0) | ((unsigned)f2bf(y1) << 16);
    c1 = c2; c2 = nx;
  }
}

extern "C" void kernel_launch(void* const* d_in, const int* in_sizes, int n_in,
                              void* d_out, int out_size, void* d_ws, size_t ws_size,
                              hipStream_t stream) {
  const float* x    = (const float*)d_in[0];
  const float* w_ud = (const float*)d_in[1];
  const float* b_ud = (const float*)d_in[2];
  const float* w_du = (const float*)d_in[3];
  const float* b_du = (const float*)d_in[4];
  const float* w_lr = (const float*)d_in[5];
  const float* b_lr = (const float*)d_in[6];
  const float* w_rl = (const float*)d_in[7];
  const float* b_rl = (const float*)d_in[8];

  // ws: A[0,64M) Bb[64M,128M) Cc[128M,192M) A2 x4 @192M
  unsigned short* A  = (unsigned short*)d_ws;
  unsigned short* Bb = (unsigned short*)((char*)d_ws + 67108864);
  unsigned short* Cc = (unsigned short*)((char*)d_ws + 134217728);
  unsigned short* A2 = (unsigned short*)((char*)d_ws + 201326592);
  unsigned short* A2_ud = A2 + 0 * (C_ * KDIM_);
  unsigned short* A2_du = A2 + 1 * (C_ * KDIM_);
  unsigned short* A2_lr = A2 + 2 * (C_ * KDIM_);
  unsigned short* A2_rl = A2 + 3 * (C_ * KDIM_);

  dim3 pg((C_ * KDIM_ + 255) / 256);
  prep_w<<<pg, 256, 0, stream>>>(w_ud, A2_ud);
  prep_w<<<pg, 256, 0, stream>>>(w_du, A2_du);
  prep_w<<<pg, 256, 0, stream>>>(w_lr, A2_lr);
  prep_w<<<pg, 256, 0, stream>>>(w_rl, A2_rl);

  transpose_in<<<dim3(4, H_, B_), 256, 0, stream>>>(x, A);

  conv2<0><<<dim3(16, B_), 256, 0, stream>>>(A, Bb, A2_ud, b_ud);
  scanH<0><<<512, 256, 0, stream>>>(Bb, A);

  conv2<0><<<dim3(16, B_), 256, 0, stream>>>(Bb, Cc, A2_du, b_du);
  scanH<1><<<512, 256, 0, stream>>>(Cc, Bb);

  conv2<1><<<dim3(16, B_), 256, 0, stream>>>(Cc, A, A2_lr, b_lr);
  scanW<0><<<256, 256, 0, stream>>>(A, Cc);

  conv2<1><<<dim3(16, B_), 256, 0, stream>>>(A, Bb, A2_rl, b_rl);
  scanW<1><<<256, 256, 0, stream>>>(Bb, A);

  transpose_out<<<dim3(4, H_, B_), 256, 0, stream>>>(Bb, (float*)d_out);
}

// Round 4
// 430.552 us; speedup vs baseline: 6.4287x; 1.0450x over previous
//
#include <hip/hip_runtime.h>

#define B_ 16
#define C_ 64
#define H_ 128
#define W_ 256
#define K_ 9
#define KDIM_ (K_*C_)            // 576
#define TOT_ ((size_t)B_*C_*H_*W_)

typedef __attribute__((ext_vector_type(8))) short short8_t;
typedef __attribute__((ext_vector_type(4))) float f32x4;

static __device__ __forceinline__ float bf2f(unsigned short u) {
  union { unsigned int i; float f; } v; v.i = ((unsigned int)u) << 16; return v.f;
}
static __device__ __forceinline__ unsigned short f2bf(float f) {
  union { float f; unsigned int i; } v; v.f = f;
  unsigned int r = v.i + 0x7FFF + ((v.i >> 16) & 1);   // RNE
  return (unsigned short)(r >> 16);
}

// async global->LDS, 16B per lane; lds ptr must be wave-uniform
static __device__ __forceinline__ void gload_lds16(const void* g, void* l) {
  __builtin_amdgcn_global_load_lds(
      (const __attribute__((address_space(1))) unsigned int*)g,
      (__attribute__((address_space(3))) unsigned int*)l, 16, 0, 0);
}

// All 4 weight tensors [co][ci][kk] fp32 -> A2 chunk layout (16B chunk = 8
// consecutive k for one co): A2[(c*64+co)*8 + (k&7)], c = k>>3, k = kk*64+ci.
__global__ __launch_bounds__(256) void prep_w_all(const float* __restrict__ w0,
                                                  const float* __restrict__ w1,
                                                  const float* __restrict__ w2,
                                                  const float* __restrict__ w3,
                                                  unsigned short* __restrict__ A2) {
  int idx = blockIdx.x * 256 + threadIdx.x;
  if (idx >= C_ * KDIM_) return;
  int which = blockIdx.y;
  const float* w = (which == 0) ? w0 : (which == 1) ? w1 : (which == 2) ? w2 : w3;
  unsigned short* out = A2 + (size_t)which * (C_ * KDIM_);
  int co = idx / KDIM_, k = idx % KDIM_;
  int ci = k & 63, kk = k >> 6;
  out[((size_t)(k >> 3) * 64 + co) * 8 + (k & 7)] =
      f2bf(w[((size_t)co * C_ + ci) * K_ + kk]);
}

// fp32 NCHW -> bf16 ci-minor [b][h][w][ci] (packed uint stores)
__global__ __launch_bounds__(256) void transpose_in(const float* __restrict__ x,
                                                    unsigned short* __restrict__ Xt) {
  __shared__ float tile[64][65];
  const int w0 = blockIdx.x * 64, h = blockIdx.y, b = blockIdx.z;
  const int t = threadIdx.x;
#pragma unroll
  for (int rep = 0; rep < 16; ++rep) {
    int idx = rep * 256 + t;
    int ci = idx >> 6, wl = idx & 63;
    tile[ci][wl] = x[((size_t)(b * C_ + ci) * H_ + h) * W_ + w0 + wl];
  }
  __syncthreads();
#pragma unroll
  for (int rep = 0; rep < 8; ++rep) {
    int idx = rep * 256 + t;
    int wl = idx >> 5, cp = idx & 31;
    unsigned v = (unsigned)f2bf(tile[cp*2][wl]) | ((unsigned)f2bf(tile[cp*2+1][wl]) << 16);
    *(unsigned*)(Xt + ((size_t)(b * H_ + h) * W_ + w0 + wl) * C_ + cp * 2) = v;
  }
}

// bf16 ci-minor -> fp32 NCHW (final output)
__global__ __launch_bounds__(256) void transpose_out(const unsigned short* __restrict__ F,
                                                     float* __restrict__ out) {
  __shared__ float tile[64][65];
  const int w0 = blockIdx.x * 64, h = blockIdx.y, b = blockIdx.z;
  const int t = threadIdx.x;
#pragma unroll
  for (int rep = 0; rep < 8; ++rep) {
    int idx = rep * 256 + t;
    int wl = idx >> 5, cp = idx & 31;
    unsigned v = *(const unsigned*)(F + ((size_t)(b * H_ + h) * W_ + w0 + wl) * C_ + cp * 2);
    tile[cp*2][wl]   = bf2f((unsigned short)v);
    tile[cp*2+1][wl] = bf2f((unsigned short)(v >> 16));
  }
  __syncthreads();
#pragma unroll
  for (int rep = 0; rep < 16; ++rep) {
    int idx = rep * 256 + t;
    int ci = idx >> 6, wl = idx & 63;
    out[((size_t)(b * C_ + ci) * H_ + h) * W_ + w0 + wl] = tile[ci][wl];
  }
}

// Persistent-block MFMA conv, 2-phase pipeline.
// A operand: ALL 72 fragments preloaded to registers per wave (unified 512-reg
// file @ 1 wave/SIMD) -> K-loop does only 4 ds_read_b128 + 16 MFMA per step.
// x tiles in LDS, XOR-swizzled per 16B chunk (slot s of row r holds chunk
// s^(r&7)), staged via linear global_load_lds with pre-swizzled global source.
// MODE 0: conv along W; block=(h-group of 8, b); wave wv owns w in [wv*64,+64).
// MODE 1: conv along H; block=(w-group of 16, b); wave -> (strip=wv>>1, half=wv&1).
template<int MODE>
__global__ __launch_bounds__(256, 1) void conv2(const unsigned short* __restrict__ X,
                                                unsigned short* __restrict__ Y,
                                                const unsigned short* __restrict__ A2,
                                                const float* __restrict__ bias) {
  constexpr int XBUF  = (MODE == 0) ? 33792 : 34816;   // bytes per x buffer
  constexpr int STRIP = 17408;                          // MODE1 strip bytes (136*128)
  __shared__ __align__(16) char lds[2 * XBUF];
  char* xbuf0 = lds;
  char* xbuf1 = lds + XBUF;

  const int t = threadIdx.x, b = blockIdx.y;
  const int lane = t & 63, wv = t >> 6;
  const int llo = lane & 15, lhi = lane >> 4;
  const int base0 = (MODE == 0) ? blockIdx.x * 8 : blockIdx.x * 16;

  // ---- A -> registers (72 x 16B per lane; all indices compile-time) ----
  short8_t areg[18][4];
#pragma unroll
  for (int step = 0; step < 18; ++step)
#pragma unroll
    for (int j = 0; j < 4; ++j)
      areg[step][j] = *(const short8_t*)(A2 + ((size_t)((step * 4 + lhi) * 64 + j * 16 + llo)) * 8);

  // ---- zero pad rows (both buffers; stage never touches pads) ----
  if (MODE == 0) {
    if (t < 128) {                            // rows 0..3, 260..263 x 2 bufs
      short8_t z = {0,0,0,0,0,0,0,0};
      int bufId = t >> 6, q = (t >> 3) & 7, slot = t & 7;
      int r = (q < 4) ? q : 256 + q;
      *(short8_t*)((bufId ? xbuf1 : xbuf0) + r * 128 + slot * 16) = z;
    }
  } else {
    {                                         // 2 bufs x 2 strips x 8 rows x 8 slots
      short8_t z = {0,0,0,0,0,0,0,0};
      int bufId = t >> 7, s = (t >> 6) & 1, q = (t >> 3) & 7, slot = t & 7;
      int r = (q < 4) ? q : 128 + q;
      *(short8_t*)((bufId ? xbuf1 : xbuf0) + s * STRIP + r * 128 + slot * 16) = z;
    }
  }

  auto stageM0 = [&](char* xb, int h) {
    const char* src = (const char*)X + ((size_t)(b * H_ + h) * W_) * 128;
#pragma unroll
    for (int j = 0; j < 8; ++j) {
      int row0 = 4 + wv * 64 + j * 8;
      int r = row0 + (lane >> 3);
      int w = r - 4;
      int chunk = (lane & 7) ^ (r & 7);
      gload_lds16(src + (size_t)w * 128 + chunk * 16, xb + row0 * 128);
    }
  };
  auto stageM1 = [&](char* xb, int w0) {
#pragma unroll
    for (int j = 0; j < 8; ++j) {
      int m = wv * 8 + j;                     // 0..31
      int s = m >> 4;
      int row0 = 4 + (m & 15) * 8;
      int r = row0 + (lane >> 3);
      int h = r - 4;
      int chunk = (lane & 7) ^ (r & 7);
      gload_lds16((const char*)X + ((size_t)(b * H_ + h) * W_ + w0 + s) * 128 + chunk * 16,
                  xb + s * STRIP + row0 * 128);
    }
  };

  if (MODE == 0) stageM0(xbuf0, base0); else stageM1(xbuf0, base0);
  __syncthreads();   // drains A-reg loads + stage0

  int nbase, sbase;
  if (MODE == 0) { nbase = wv * 64; sbase = 0; }
  else           { nbase = (wv & 1) * 64; sbase = (wv >> 1) * STRIP; }

  for (int it = 0; it < 8; ++it) {
    char* cur = (it & 1) ? xbuf1 : xbuf0;
    char* nxt = (it & 1) ? xbuf0 : xbuf1;
    if (it + 1 < 8) {                          // issue next stage BEFORE compute
      if (MODE == 0) stageM0(nxt, base0 + it + 1);
      else           stageM1(nxt, base0 + (it + 1) * 2);
    }

    const char* xb = cur + sbase;
    f32x4 acc[4][4];
#pragma unroll
    for (int i = 0; i < 4; ++i)
#pragma unroll
      for (int j = 0; j < 4; ++j) { f32x4 z = {0.f,0.f,0.f,0.f}; acc[i][j] = z; }

#pragma unroll
    for (int step = 0; step < 18; ++step) {    // FULL unroll: areg idx compile-time
      const int kk = step >> 1;
      const int cg = (step & 1) * 4 + lhi;
      short8_t bfr[4];
#pragma unroll
      for (int i = 0; i < 4; ++i) {
        int r = nbase + i * 16 + llo + kk;
        bfr[i] = *(const short8_t*)(xb + r * 128 + ((cg ^ (r & 7)) * 16));
      }
#pragma unroll
      for (int i = 0; i < 4; ++i)
#pragma unroll
        for (int j = 0; j < 4; ++j)
          acc[i][j] = __builtin_amdgcn_mfma_f32_16x16x32_bf16(areg[step][j], bfr[i], acc[i][j], 0, 0, 0);
    }

    // epilogue: +bias, pack 4 consecutive co (8B stores)
#pragma unroll
    for (int j = 0; j < 4; ++j) {
      const int cb = j * 16 + lhi * 4;
      const float4 bv = *(const float4*)(bias + cb);
#pragma unroll
      for (int i = 0; i < 4; ++i) {
        const int n = nbase + i * 16 + llo;
        size_t off;
        if (MODE == 0) { int h = base0 + it;
          off = ((size_t)(b * H_ + h) * W_ + n) * C_ + cb; }
        else { int w = base0 + it * 2 + (wv >> 1);
          off = ((size_t)(b * H_ + n) * W_ + w) * C_ + cb; }
        short4 o;
        o.x = (short)f2bf(acc[i][j][0] + bv.x);
        o.y = (short)f2bf(acc[i][j][1] + bv.y);
        o.z = (short)f2bf(acc[i][j][2] + bv.z);
        o.w = (short)f2bf(acc[i][j][3] + bv.w);
        *(short4*)(Y + off) = o;
      }
    }
    __syncthreads();   // stage(it+1) latency already covered by compute
  }
}

// Scan along H, in-place, 2 ci (uint) per thread, depth-2 prefetch.
template<int REV>
__global__ __launch_bounds__(256) void scanH(unsigned short* __restrict__ buf,
                                             const unsigned short* __restrict__ prev) {
  int idx = blockIdx.x * 256 + threadIdx.x;      // B*W*32
  int cp = idx & 31, w = (idx >> 5) & 255, b = idx >> 13;
  const ptrdiff_t dh = (REV ? -1 : 1) * (ptrdiff_t)(W_ * C_);
  size_t off = ((size_t)(b * H_ + (REV ? H_ - 1 : 0)) * W_ + w) * C_ + cp * 2;
  unsigned pv = *(const unsigned*)(prev + off);
  *(unsigned*)(buf + off) = pv;
  float y0 = bf2f((unsigned short)pv), y1 = bf2f((unsigned short)(pv >> 16));
  unsigned c1 = *(const unsigned*)(buf + off + dh);
  unsigned c2 = *(const unsigned*)(buf + off + 2 * dh);
  for (int s = 1; s < H_; ++s) {
    off += dh;
    unsigned nx = (s + 2 < H_) ? *(const unsigned*)(buf + off + 2 * dh) : 0u;
    y0 = fmaxf(bf2f((unsigned short)c1) + y0, 0.f);
    y1 = fmaxf(bf2f((unsigned short)(c1 >> 16)) + y1, 0.f);
    *(unsigned*)(buf + off) = (unsigned)f2bf(y0) | ((unsigned)f2bf(y1) << 16);
    c1 = c2; c2 = nx;
  }
}

// Scan along W, in-place bf16, 2 ci per thread, depth-2 prefetch.
template<int REV>
__global__ __launch_bounds__(256) void scanW(unsigned short* __restrict__ buf,
                                             const unsigned short* __restrict__ prev) {
  int idx = blockIdx.x * 256 + threadIdx.x;      // B*H*32
  int cp = idx & 31, h = (idx >> 5) & 127, b = idx >> 12;
  const ptrdiff_t dw = (REV ? -1 : 1) * (ptrdiff_t)C_;
  size_t off = ((size_t)(b * H_ + h) * W_ + (REV ? W_ - 1 : 0)) * C_ + cp * 2;
  unsigned pv = *(const unsigned*)(prev + off);
  *(unsigned*)(buf + off) = pv;
  float y0 = bf2f((unsigned short)pv), y1 = bf2f((unsigned short)(pv >> 16));
  unsigned c1 = *(const unsigned*)(buf + off + dw);
  unsigned c2 = *(const unsigned*)(buf + off + 2 * dw);
  for (int s = 1; s < W_; ++s) {
    off += dw;
    unsigned nx = (s + 2 < W_) ? *(const unsigned*)(buf + off + 2 * dw) : 0u;
    y0 = fmaxf(bf2f((unsigned short)c1) + y0, 0.f);
    y1 = fmaxf(bf2f((unsigned short)(c1 >> 16)) + y1, 0.f);
    *(unsigned*)(buf + off) = (unsigned)f2bf(y0) | ((unsigned)f2bf(y1) << 16);
    c1 = c2; c2 = nx;
  }
}

extern "C" void kernel_launch(void* const* d_in, const int* in_sizes, int n_in,
                              void* d_out, int out_size, void* d_ws, size_t ws_size,
                              hipStream_t stream) {
  const float* x    = (const float*)d_in[0];
  const float* w_ud = (const float*)d_in[1];
  const float* b_ud = (const float*)d_in[2];
  const float* w_du = (const float*)d_in[3];
  const float* b_du = (const float*)d_in[4];
  const float* w_lr = (const float*)d_in[5];
  const float* b_lr = (const float*)d_in[6];
  const float* w_rl = (const float*)d_in[7];
  const float* b_rl = (const float*)d_in[8];

  // ws: A[0,64M) Bb[64M,128M) Cc[128M,192M) A2 x4 @192M
  unsigned short* A  = (unsigned short*)d_ws;
  unsigned short* Bb = (unsigned short*)((char*)d_ws + 67108864);
  unsigned short* Cc = (unsigned short*)((char*)d_ws + 134217728);
  unsigned short* A2 = (unsigned short*)((char*)d_ws + 201326592);
  unsigned short* A2_ud = A2 + 0 * (C_ * KDIM_);
  unsigned short* A2_du = A2 + 1 * (C_ * KDIM_);
  unsigned short* A2_lr = A2 + 2 * (C_ * KDIM_);
  unsigned short* A2_rl = A2 + 3 * (C_ * KDIM_);

  dim3 pg((C_ * KDIM_ + 255) / 256, 4);
  prep_w_all<<<pg, 256, 0, stream>>>(w_ud, w_du, w_lr, w_rl, A2);

  transpose_in<<<dim3(4, H_, B_), 256, 0, stream>>>(x, A);

  conv2<0><<<dim3(16, B_), 256, 0, stream>>>(A, Bb, A2_ud, b_ud);
  scanH<0><<<512, 256, 0, stream>>>(Bb, A);

  conv2<0><<<dim3(16, B_), 256, 0, stream>>>(Bb, Cc, A2_du, b_du);
  scanH<1><<<512, 256, 0, stream>>>(Cc, Bb);

  conv2<1><<<dim3(16, B_), 256, 0, stream>>>(Cc, A, A2_lr, b_lr);
  scanW<0><<<256, 256, 0, stream>>>(A, Cc);

  conv2<1><<<dim3(16, B_), 256, 0, stream>>>(A, Bb, A2_rl, b_rl);
  scanW<1><<<256, 256, 0, stream>>>(Bb, A);

  transpose_out<<<dim3(4, H_, B_), 256, 0, stream>>>(Bb, (float*)d_out);
}

// Round 5
// 399.371 us; speedup vs baseline: 6.9306x; 1.0781x over previous
//
#include <hip/hip_runtime.h>

#define B_ 16
#define C_ 64
#define H_ 128
#define W_ 256
#define K_ 9
#define KDIM_ (K_*C_)            // 576

typedef __attribute__((ext_vector_type(8))) short short8_t;
typedef __attribute__((ext_vector_type(4))) float f32x4;

static __device__ __forceinline__ float bf2f(unsigned short u) {
  union { unsigned int i; float f; } v; v.i = ((unsigned int)u) << 16; return v.f;
}
static __device__ __forceinline__ unsigned short f2bf(float f) {
  union { float f; unsigned int i; } v; v.f = f;
  unsigned int r = v.i + 0x7FFF + ((v.i >> 16) & 1);   // RNE
  return (unsigned short)(r >> 16);
}

// async global->LDS, 16B per lane; lds ptr wave-uniform, lanes fill +lane*16
static __device__ __forceinline__ void gload_lds16(const void* g, void* l) {
  __builtin_amdgcn_global_load_lds(
      (const __attribute__((address_space(1))) unsigned int*)g,
      (__attribute__((address_space(3))) unsigned int*)l, 16, 0, 0);
}

// All 4 weight tensors [co][ci][kk] fp32 -> A2 chunk layout (16B chunk = 8
// consecutive k for one co): A2[(c*64+co)*8 + (k&7)], c = k>>3, k = kk*64+ci.
__global__ __launch_bounds__(256) void prep_w_all(const float* __restrict__ w0,
                                                  const float* __restrict__ w1,
                                                  const float* __restrict__ w2,
                                                  const float* __restrict__ w3,
                                                  unsigned short* __restrict__ A2) {
  int idx = blockIdx.x * 256 + threadIdx.x;
  if (idx >= C_ * KDIM_) return;
  int which = blockIdx.y;
  const float* w = (which == 0) ? w0 : (which == 1) ? w1 : (which == 2) ? w2 : w3;
  unsigned short* out = A2 + (size_t)which * (C_ * KDIM_);
  int co = idx / KDIM_, k = idx % KDIM_;
  int ci = k & 63, kk = k >> 6;
  out[((size_t)(k >> 3) * 64 + co) * 8 + (k & 7)] =
      f2bf(w[((size_t)co * C_ + ci) * K_ + kk]);
}

// fp32 NCHW -> bf16 ci-minor [b][h][w][ci]
__global__ __launch_bounds__(256) void transpose_in(const float* __restrict__ x,
                                                    unsigned short* __restrict__ Xt) {
  __shared__ float tile[64][65];
  const int w0 = blockIdx.x * 64, h = blockIdx.y, b = blockIdx.z;
  const int t = threadIdx.x;
#pragma unroll
  for (int rep = 0; rep < 16; ++rep) {
    int idx = rep * 256 + t;
    int ci = idx >> 6, wl = idx & 63;
    tile[ci][wl] = x[((size_t)(b * C_ + ci) * H_ + h) * W_ + w0 + wl];
  }
  __syncthreads();
#pragma unroll
  for (int rep = 0; rep < 8; ++rep) {
    int idx = rep * 256 + t;
    int wl = idx >> 5, cp = idx & 31;
    unsigned v = (unsigned)f2bf(tile[cp*2][wl]) | ((unsigned)f2bf(tile[cp*2+1][wl]) << 16);
    *(unsigned*)(Xt + ((size_t)(b * H_ + h) * W_ + w0 + wl) * C_ + cp * 2) = v;
  }
}

// bf16 ci-minor -> fp32 NCHW (final output)
__global__ __launch_bounds__(256) void transpose_out(const unsigned short* __restrict__ F,
                                                     float* __restrict__ out) {
  __shared__ float tile[64][65];
  const int w0 = blockIdx.x * 64, h = blockIdx.y, b = blockIdx.z;
  const int t = threadIdx.x;
#pragma unroll
  for (int rep = 0; rep < 8; ++rep) {
    int idx = rep * 256 + t;
    int wl = idx >> 5, cp = idx & 31;
    unsigned v = *(const unsigned*)(F + ((size_t)(b * H_ + h) * W_ + w0 + wl) * C_ + cp * 2);
    tile[cp*2][wl]   = bf2f((unsigned short)v);
    tile[cp*2+1][wl] = bf2f((unsigned short)(v >> 16));
  }
  __syncthreads();
#pragma unroll
  for (int rep = 0; rep < 16; ++rep) {
    int idx = rep * 256 + t;
    int ci = idx >> 6, wl = idx & 63;
    out[((size_t)(b * C_ + ci) * H_ + h) * W_ + w0 + wl] = tile[ci][wl];
  }
}

// ===== Fused conv-along-W + scan-along-H (sweeps 1 & 2) =====
// Grid (16 w-chunks, 16 b), 256 thr. Wave wv owns co slice [wv*16, +16).
// Per h: conv M=16co x N=16w x K=576 into regs, y = relu(conv + bias + y),
// store bf16. Quad-buffered 3KB row staging (global_load_lds, chunk-XOR
// swizzle via pre-swizzled source); raw s_barrier + counted vmcnt(3) keeps
// 2 stages in flight across barriers (each wave's own in-order vmcnt).
template<int REV>
__global__ __launch_bounds__(256, 1) void fused_cw_sh(const unsigned short* __restrict__ X,
                                                      unsigned short* __restrict__ Y,
                                                      const unsigned short* __restrict__ A2,
                                                      const float* __restrict__ bias,
                                                      const unsigned short* __restrict__ zeropage) {
  __shared__ __align__(16) char lds[4*18432 + 4*3072];   // A slices + stage slots
  char* Asl   = lds;
  char* slots = lds + 73728;

  const int t = threadIdx.x, b = blockIdx.y;
  const int lane = t & 63, wv = t >> 6;
  const int llo = lane & 15, lhi = lane >> 4;
  const int w0 = blockIdx.x * 16;

  // A slice -> LDS (18 x 1KB per wave), then -> regs
#pragma unroll
  for (int m = 0; m < 18; ++m)
    gload_lds16(A2 + ((size_t)((m*4 + lhi)*64 + wv*16 + llo)) * 8,
                Asl + wv*18432 + m*1024);

  auto stage = [&](int h, int s) {
    if (wv < 3) {
      int r = wv*8 + (lane >> 3);
      int w = w0 - 4 + r;
      int chunk = (lane & 7) ^ (r & 7);
      const void* src = ((unsigned)w < (unsigned)W_)
        ? (const void*)((const char*)X + (((size_t)(b*H_ + h)*W_ + w)*64 + chunk*8)*2)
        : (const void*)((const char*)zeropage + (lane & 7)*16);
      gload_lds16(src, slots + s*3072 + wv*1024);
    }
  };

  const int h0 = REV ? H_-1 : 0;
  const int dh = REV ? -1 : 1;
  stage(h0,        h0 & 3);
  stage(h0 + dh,  (h0 + dh) & 3);
  stage(h0 + 2*dh, (h0 + 2*dh) & 3);
  asm volatile("s_waitcnt vmcnt(0)\ns_barrier" ::: "memory");

  short8_t areg[18];
#pragma unroll
  for (int m = 0; m < 18; ++m)
    areg[m] = *(const short8_t*)(Asl + wv*18432 + m*1024 + lane*16);

  const float4 bv = *(const float4*)(bias + wv*16 + lhi*4);

  float y0_, y1_, y2_, y3_;
  {
    // h0 passthrough: y = x[h0], store unchanged
    int row = 4 + llo;
    int c0 = wv*2 + (lhi >> 1);
    const uint2 v = *(const uint2*)(slots + (h0 & 3)*3072 + row*128
                                    + ((c0 ^ (row & 7)) << 4) + (lhi & 1)*8);
    y0_ = bf2f((unsigned short)v.x); y1_ = bf2f((unsigned short)(v.x >> 16));
    y2_ = bf2f((unsigned short)v.y); y3_ = bf2f((unsigned short)(v.y >> 16));
    size_t off = ((size_t)(b*H_ + h0)*W_ + w0 + llo)*64 + wv*16 + lhi*4;
    uint2 ov; ov.x = v.x; ov.y = v.y;
    *(uint2*)(Y + off) = ov;
    stage(h0 + 3*dh, (h0 + 3*dh) & 3);
    asm volatile("s_waitcnt vmcnt(3)\ns_barrier" ::: "memory");
  }

  for (int i = 1; i < H_; ++i) {
    const int h = h0 + i*dh;
    const char* xb = slots + (h & 3)*3072;
    f32x4 acc0 = {0.f,0.f,0.f,0.f}, acc1 = {0.f,0.f,0.f,0.f};
#pragma unroll
    for (int step = 0; step < 18; ++step) {
      const int kk = step >> 1;
      const int cg = (step & 1)*4 + lhi;
      const int row = llo + kk;
      short8_t bfr = *(const short8_t*)(xb + row*128 + ((cg ^ (row & 7)) << 4));
      if (step & 1) acc1 = __builtin_amdgcn_mfma_f32_16x16x32_bf16(areg[step], bfr, acc1, 0, 0, 0);
      else          acc0 = __builtin_amdgcn_mfma_f32_16x16x32_bf16(areg[step], bfr, acc0, 0, 0, 0);
    }
    f32x4 s = acc0 + acc1;
    y0_ = fmaxf(s[0] + bv.x + y0_, 0.f);
    y1_ = fmaxf(s[1] + bv.y + y1_, 0.f);
    y2_ = fmaxf(s[2] + bv.z + y2_, 0.f);
    y3_ = fmaxf(s[3] + bv.w + y3_, 0.f);
    size_t off = ((size_t)(b*H_ + h)*W_ + w0 + llo)*64 + wv*16 + lhi*4;
    uint2 ov;
    ov.x = (unsigned)f2bf(y0_) | ((unsigned)f2bf(y1_) << 16);
    ov.y = (unsigned)f2bf(y2_) | ((unsigned)f2bf(y3_) << 16);
    *(uint2*)(Y + off) = ov;
    if (i + 3 < H_) stage(h + 3*dh, (h + 3*dh) & 3);
    asm volatile("s_waitcnt vmcnt(3)\ns_barrier" ::: "memory");
  }
}

// Persistent-block MFMA conv along H (sweep 3/4 conv), unchanged from R4.
__global__ __launch_bounds__(256, 1) void conv2_m1(const unsigned short* __restrict__ X,
                                                   unsigned short* __restrict__ Y,
                                                   const unsigned short* __restrict__ A2,
                                                   const float* __restrict__ bias) {
  constexpr int XBUF  = 34816;
  constexpr int STRIP = 17408;
  __shared__ __align__(16) char lds[2 * XBUF];
  char* xbuf0 = lds;
  char* xbuf1 = lds + XBUF;

  const int t = threadIdx.x, b = blockIdx.y;
  const int lane = t & 63, wv = t >> 6;
  const int llo = lane & 15, lhi = lane >> 4;
  const int base0 = blockIdx.x * 16;

  short8_t areg[18][4];
#pragma unroll
  for (int step = 0; step < 18; ++step)
#pragma unroll
    for (int j = 0; j < 4; ++j)
      areg[step][j] = *(const short8_t*)(A2 + ((size_t)((step * 4 + lhi) * 64 + j * 16 + llo)) * 8);

  {
    short8_t z = {0,0,0,0,0,0,0,0};
    int bufId = t >> 7, s = (t >> 6) & 1, q = (t >> 3) & 7, slot = t & 7;
    int r = (q < 4) ? q : 128 + q;
    *(short8_t*)((bufId ? xbuf1 : xbuf0) + s * STRIP + r * 128 + slot * 16) = z;
  }

  auto stageM1 = [&](char* xb, int w0) {
#pragma unroll
    for (int j = 0; j < 8; ++j) {
      int m = wv * 8 + j;
      int s = m >> 4;
      int row0 = 4 + (m & 15) * 8;
      int r = row0 + (lane >> 3);
      int h = r - 4;
      int chunk = (lane & 7) ^ (r & 7);
      gload_lds16((const char*)X + ((size_t)(b * H_ + h) * W_ + w0 + s) * 128 + chunk * 16,
                  xb + s * STRIP + row0 * 128);
    }
  };

  stageM1(xbuf0, base0);
  __syncthreads();

  const int nbase = (wv & 1) * 64;
  const int sbase = (wv >> 1) * STRIP;

  for (int it = 0; it < 8; ++it) {
    char* cur = (it & 1) ? xbuf1 : xbuf0;
    char* nxt = (it & 1) ? xbuf0 : xbuf1;
    if (it + 1 < 8) stageM1(nxt, base0 + (it + 1) * 2);

    const char* xb = cur + sbase;
    f32x4 acc[4][4];
#pragma unroll
    for (int i = 0; i < 4; ++i)
#pragma unroll
      for (int j = 0; j < 4; ++j) { f32x4 z = {0.f,0.f,0.f,0.f}; acc[i][j] = z; }

#pragma unroll
    for (int step = 0; step < 18; ++step) {
      const int kk = step >> 1;
      const int cg = (step & 1) * 4 + lhi;
      short8_t bfr[4];
#pragma unroll
      for (int i = 0; i < 4; ++i) {
        int r = nbase + i * 16 + llo + kk;
        bfr[i] = *(const short8_t*)(xb + r * 128 + ((cg ^ (r & 7)) * 16));
      }
#pragma unroll
      for (int i = 0; i < 4; ++i)
#pragma unroll
        for (int j = 0; j < 4; ++j)
          acc[i][j] = __builtin_amdgcn_mfma_f32_16x16x32_bf16(areg[step][j], bfr[i], acc[i][j], 0, 0, 0);
    }

#pragma unroll
    for (int j = 0; j < 4; ++j) {
      const int cb = j * 16 + lhi * 4;
      const float4 bvv = *(const float4*)(bias + cb);
#pragma unroll
      for (int i = 0; i < 4; ++i) {
        const int n = nbase + i * 16 + llo;
        int w = base0 + it * 2 + (wv >> 1);
        size_t off = ((size_t)(b * H_ + n) * W_ + w) * C_ + cb;
        short4 o;
        o.x = (short)f2bf(acc[i][j][0] + bvv.x);
        o.y = (short)f2bf(acc[i][j][1] + bvv.y);
        o.z = (short)f2bf(acc[i][j][2] + bvv.z);
        o.w = (short)f2bf(acc[i][j][3] + bvv.w);
        *(short4*)(Y + off) = o;
      }
    }
    __syncthreads();
  }
}

// Scan along W, in-place bf16, 4 ci (uint2, 8B) per thread, depth-8 prefetch.
template<int REV>
__global__ __launch_bounds__(256) void scanW2(unsigned short* __restrict__ buf,
                                              const unsigned short* __restrict__ prev) {
  int idx = blockIdx.x * 256 + threadIdx.x;      // B*H*16
  int cq = idx & 15, h = (idx >> 4) & 127, b = idx >> 11;
  const ptrdiff_t dw = (REV ? -1 : 1) * (ptrdiff_t)C_;
  size_t off = ((size_t)(b * H_ + h) * W_ + (REV ? W_ - 1 : 0)) * C_ + cq * 4;
  uint2 pv = *(const uint2*)(prev + off);
  *(uint2*)(buf + off) = pv;
  float y0 = bf2f((unsigned short)pv.x), y1 = bf2f((unsigned short)(pv.x >> 16));
  float y2 = bf2f((unsigned short)pv.y), y3 = bf2f((unsigned short)(pv.y >> 16));
  uint2 c[8];
#pragma unroll
  for (int j = 0; j < 8; ++j) c[j] = *(const uint2*)(buf + off + (ptrdiff_t)(j + 1) * dw);
  for (int base = 1; base < W_; base += 8) {
#pragma unroll
    for (int j = 0; j < 8; ++j) {
      int s = base + j;
      if (s < W_) {
        off += dw;
        y0 = fmaxf(bf2f((unsigned short)c[j].x) + y0, 0.f);
        y1 = fmaxf(bf2f((unsigned short)(c[j].x >> 16)) + y1, 0.f);
        y2 = fmaxf(bf2f((unsigned short)c[j].y) + y2, 0.f);
        y3 = fmaxf(bf2f((unsigned short)(c[j].y >> 16)) + y3, 0.f);
        uint2 ov;
        ov.x = (unsigned)f2bf(y0) | ((unsigned)f2bf(y1) << 16);
        ov.y = (unsigned)f2bf(y2) | ((unsigned)f2bf(y3) << 16);
        *(uint2*)(buf + off) = ov;
        if (s + 8 < W_) c[j] = *(const uint2*)(buf + off + 8 * dw);
      }
    }
  }
}

extern "C" void kernel_launch(void* const* d_in, const int* in_sizes, int n_in,
                              void* d_out, int out_size, void* d_ws, size_t ws_size,
                              hipStream_t stream) {
  const float* x    = (const float*)d_in[0];
  const float* w_ud = (const float*)d_in[1];
  const float* b_ud = (const float*)d_in[2];
  const float* w_du = (const float*)d_in[3];
  const float* b_du = (const float*)d_in[4];
  const float* w_lr = (const float*)d_in[5];
  const float* b_lr = (const float*)d_in[6];
  const float* w_rl = (const float*)d_in[7];
  const float* b_rl = (const float*)d_in[8];

  // ws: A[0,64M) Bb[64M,128M) Cc[128M,192M) A2 @192M, zeropage @192M+1M
  unsigned short* A  = (unsigned short*)d_ws;
  unsigned short* Bb = (unsigned short*)((char*)d_ws + 67108864);
  unsigned short* Cc = (unsigned short*)((char*)d_ws + 134217728);
  unsigned short* A2 = (unsigned short*)((char*)d_ws + 201326592);
  unsigned short* ZP = (unsigned short*)((char*)d_ws + 202375168);
  unsigned short* A2_ud = A2 + 0 * (C_ * KDIM_);
  unsigned short* A2_du = A2 + 1 * (C_ * KDIM_);
  unsigned short* A2_lr = A2 + 2 * (C_ * KDIM_);
  unsigned short* A2_rl = A2 + 3 * (C_ * KDIM_);

  hipMemsetAsync(ZP, 0, 1024, stream);

  dim3 pg((C_ * KDIM_ + 255) / 256, 4);
  prep_w_all<<<pg, 256, 0, stream>>>(w_ud, w_du, w_lr, w_rl, A2);

  transpose_in<<<dim3(4, H_, B_), 256, 0, stream>>>(x, A);

  // sweeps 1 & 2: fused conv-along-W + scan-along-H
  fused_cw_sh<0><<<dim3(16, B_), 256, 0, stream>>>(A,  Bb, A2_ud, b_ud, ZP);
  fused_cw_sh<1><<<dim3(16, B_), 256, 0, stream>>>(Bb, Cc, A2_du, b_du, ZP);

  // sweep 3: conv along H + scan along W (fwd)
  conv2_m1<<<dim3(16, B_), 256, 0, stream>>>(Cc, A, A2_lr, b_lr);
  scanW2<0><<<128, 256, 0, stream>>>(A, Cc);

  // sweep 4: conv along H + scan along W (rev)
  conv2_m1<<<dim3(16, B_), 256, 0, stream>>>(A, Bb, A2_rl, b_rl);
  scanW2<1><<<128, 256, 0, stream>>>(Bb, A);

  transpose_out<<<dim3(4, H_, B_), 256, 0, stream>>>(Bb, (float*)d_out);
}